// Round 1
// baseline (113.190 us; speedup 1.0000x reference)
//
#include <hip/hip_runtime.h>
#include <math.h>

#define N_ 4096
#define L_ 32
#define K_ 8
#define Dc_ 64
#define Db_ 64
#define Dd_ 16
#define C_ 8
#define B_ 32
#define M_ 1000
#define LOG2PI_ 1.8378770664093453f

// output layout (floats): [0]=-elbo [1]=LL [2]=KL_z [3]=KL_s
// [4 .. 4+N*K) = rik ; then term_1 (M), term_2 (M), term_3 (M)
#define OUT_RIK 4
#define OUT_T1 (4 + N_ * K_)

__global__ __launch_bounds__(512, 4) void mm_main_kernel(
    const int* __restrict__ pidx,
    const float* __restrict__ Xc, const float* __restrict__ Xb, const int* __restrict__ Xd,
    const float* __restrict__ qm_all, const float* __restrict__ qlv_all, const float* __restrict__ qs_all,
    const float* __restrict__ Wg, const float* __restrict__ bg, const float* __restrict__ lvg,
    const float* __restrict__ Wb, const float* __restrict__ bb,
    const float* __restrict__ Wd, const float* __restrict__ bd,
    const float* __restrict__ eps,
    float* __restrict__ out, float* __restrict__ ll_partial)
{
    const int tid  = threadIdx.x;
    const int wave = tid >> 6;
    const int k    = __builtin_amdgcn_readfirstlane(wave);   // wave-uniform component index
    const int lane = tid & 63;
    const int b    = lane & 31;
    const int mo   = lane >> 5;
    const int m    = blockIdx.x * 2 + mo;
    const int start = B_ * pidx[0];

    // ---- z[l] = qm + exp(0.5*qlv) * eps  (per (b,m); registers) ----
    float z[L_];
    {
        const float4* qm4 = reinterpret_cast<const float4*>(qm_all + (size_t)(start + b) * L_);
        const float4* ql4 = reinterpret_cast<const float4*>(qlv_all + (size_t)(start + b) * L_);
        const float4* ep4 = reinterpret_cast<const float4*>(eps + ((size_t)b * M_ + m) * L_);
        #pragma unroll
        for (int i = 0; i < L_ / 4; ++i) {
            float4 qm_v = qm4[i], ql_v = ql4[i], ep_v = ep4[i];
            z[i*4+0] = qm_v.x + __expf(0.5f * ql_v.x) * ep_v.x;
            z[i*4+1] = qm_v.y + __expf(0.5f * ql_v.y) * ep_v.y;
            z[i*4+2] = qm_v.z + __expf(0.5f * ql_v.z) * ep_v.z;
            z[i*4+3] = qm_v.w + __expf(0.5f * ql_v.w) * ep_v.w;
        }
    }

    // ---- Pass A: Gaussian term t1 ----
    float t1 = 0.f;
    {
        const float* w   = Wg + (size_t)k * Dc_ * L_;
        const float* bgk = bg + k * Dc_;
        const float* lvk = lvg + k * Dc_;
        const float* xcr = Xc + b * Dc_;
        #pragma unroll 2
        for (int d = 0; d < Dc_; ++d) {
            float acc = bgk[d];
            const float4* w4 = reinterpret_cast<const float4*>(w + d * L_);
            #pragma unroll
            for (int i = 0; i < L_ / 4; ++i) {
                float4 wv = w4[i];
                acc = fmaf(wv.x, z[i*4+0], acc);
                acc = fmaf(wv.y, z[i*4+1], acc);
                acc = fmaf(wv.z, z[i*4+2], acc);
                acc = fmaf(wv.w, z[i*4+3], acc);
            }
            float lv   = lvk[d];
            float diff = xcr[d] - acc;
            t1 += LOG2PI_ + lv + diff * diff * __expf(-lv);
        }
        t1 *= -0.5f;
    }

    // ---- Pass B: Bernoulli term t2 ----
    float t2 = 0.f;
    {
        const float* w   = Wb + (size_t)k * Db_ * L_;
        const float* bbk = bb + k * Db_;
        const float* xbr = Xb + b * Db_;
        #pragma unroll 2
        for (int d = 0; d < Db_; ++d) {
            float acc = bbk[d];
            const float4* w4 = reinterpret_cast<const float4*>(w + d * L_);
            #pragma unroll
            for (int i = 0; i < L_ / 4; ++i) {
                float4 wv = w4[i];
                acc = fmaf(wv.x, z[i*4+0], acc);
                acc = fmaf(wv.y, z[i*4+1], acc);
                acc = fmaf(wv.z, z[i*4+2], acc);
                acc = fmaf(wv.w, z[i*4+3], acc);
            }
            // softplus(x) = max(x,0) + log(1+exp(-|x|))
            float sp = fmaxf(acc, 0.f) + __logf(1.f + __expf(-fabsf(acc)));
            t2 += xbr[d] * acc - sp;
        }
    }

    // ---- Pass C: categorical term t3 ----
    float t3 = 0.f;
    {
        const float* w   = Wd + (size_t)k * Dd_ * C_ * L_;
        const float* bdk = bd + k * Dd_ * C_;
        const int*   xdr = Xd + b * Dd_;
        #pragma unroll 1
        for (int d = 0; d < Dd_; ++d) {
            const float* wd0 = w + d * (C_ * L_);
            const float* bdd = bdk + d * C_;
            int xd = xdr[d];
            float lg[C_];
            #pragma unroll
            for (int c = 0; c < C_; ++c) {
                float acc = bdd[c];
                const float4* w4 = reinterpret_cast<const float4*>(wd0 + c * L_);
                #pragma unroll
                for (int i = 0; i < L_ / 4; ++i) {
                    float4 wv = w4[i];
                    acc = fmaf(wv.x, z[i*4+0], acc);
                    acc = fmaf(wv.y, z[i*4+1], acc);
                    acc = fmaf(wv.z, z[i*4+2], acc);
                    acc = fmaf(wv.w, z[i*4+3], acc);
                }
                lg[c] = acc;
            }
            float mx = lg[0];
            #pragma unroll
            for (int c = 1; c < C_; ++c) mx = fmaxf(mx, lg[c]);
            float se = 0.f;
            #pragma unroll
            for (int c = 0; c < C_; ++c) se += __expf(lg[c] - mx);
            float sel = lg[0];                       // gather via cndmask (no runtime array index)
            #pragma unroll
            for (int c = 1; c < C_; ++c) sel = (xd == c) ? lg[c] : sel;
            t3 += sel - mx - __logf(se);
        }
    }

    // ---- reductions ----
    float ll = qs_all[(size_t)(start + b) * K_ + k] * (t1 + t2 + t3);
    float r1 = t1, r2 = t2, r3 = t3;
    #pragma unroll
    for (int ofs = 1; ofs < 32; ofs <<= 1) {
        r1 += __shfl_xor(r1, ofs, 64);
        r2 += __shfl_xor(r2, ofs, 64);
        r3 += __shfl_xor(r3, ofs, 64);
        ll += __shfl_xor(ll, ofs, 64);
    }
    ll += __shfl_xor(ll, 32, 64);   // full-wave sum for LL

    __shared__ float red[8][2][3];
    __shared__ float llred[8];
    if (lane == 0)  { red[wave][0][0] = r1; red[wave][0][1] = r2; red[wave][0][2] = r3; llred[wave] = ll; }
    if (lane == 32) { red[wave][1][0] = r1; red[wave][1][1] = r2; red[wave][1][2] = r3; }
    __syncthreads();
    if (tid < 6) {
        int moi = tid / 3, ti = tid % 3;
        float s = 0.f;
        #pragma unroll
        for (int w = 0; w < 8; ++w) s += red[w][moi][ti];
        out[OUT_T1 + ti * M_ + (blockIdx.x * 2 + moi)] = s;
    }
    if (tid == 6) {
        float s = 0.f;
        #pragma unroll
        for (int w = 0; w < 8; ++w) s += llred[w];
        ll_partial[blockIdx.x] = s;
    }
}

__global__ void mm_rik_kernel(const int* __restrict__ pidx, const float* __restrict__ qs_all,
                              float* __restrict__ out)
{
    int i = blockIdx.x * blockDim.x + threadIdx.x;
    if (i >= N_ * K_) return;
    int r = i / K_, c = i % K_;
    int start = B_ * pidx[0];
    float v = 0.f;
    if (r >= start && r < start + B_) {
        const float* row = qs_all + (size_t)r * K_;
        float mx = row[0];
        #pragma unroll
        for (int j = 1; j < K_; ++j) mx = fmaxf(mx, row[j]);
        float se = 0.f;
        #pragma unroll
        for (int j = 0; j < K_; ++j) se += __expf(row[j] - mx);
        v = __expf(row[c] - mx) / se;
    }
    out[OUT_RIK + i] = v;
}

__global__ void mm_final_kernel(const int* __restrict__ pidx,
                                const float* __restrict__ qm_all, const float* __restrict__ qlv_all,
                                const float* __restrict__ qs_all,
                                const float* __restrict__ pm_all, const float* __restrict__ pv_all,
                                const float* __restrict__ pmu_all,
                                const float* __restrict__ ll_partial, int nblk,
                                float* __restrict__ out)
{
    __shared__ float sdata[512];
    __shared__ float skl[B_], sks[B_];
    int t = threadIdx.x;
    int start = B_ * pidx[0];

    float v = 0.f;
    for (int i = t; i < nblk; i += 512) v += ll_partial[i];
    sdata[t] = v;

    if (t < B_) {
        int r = start + t;
        float kl = 0.f;
        for (int l = 0; l < L_; ++l) {
            float qmv = qm_all[(size_t)r * L_ + l];
            float qlv = qlv_all[(size_t)r * L_ + l];
            float mp  = pm_all[(size_t)r * L_ + l];
            float vp  = pv_all[(size_t)r * L_ + l];
            float d   = qmv - mp;
            kl += __logf(vp) - qlv + (__expf(qlv) + d * d) / vp - 1.f;
        }
        skl[t] = 0.5f * kl;

        float qsum = 0.f, psum = 0.f;
        #pragma unroll
        for (int j = 0; j < K_; ++j) { qsum += qs_all[(size_t)r * K_ + j]; psum += pmu_all[(size_t)r * K_ + j]; }
        float ks = 0.f;
        #pragma unroll
        for (int j = 0; j < K_; ++j) {
            float qn = qs_all[(size_t)r * K_ + j] / qsum;
            float pn = pmu_all[(size_t)r * K_ + j] / psum;
            ks += qn * (__logf(qn) - __logf(pn));
        }
        sks[t] = ks;
    }
    __syncthreads();
    if (t == 0) {
        float LL = 0.f;
        for (int i = 0; i < 512; ++i) LL += sdata[i];
        float sklz = 0.f, skls = 0.f;
        for (int i = 0; i < B_; ++i) { sklz += skl[i]; skls += sks[i]; }
        float elbo = LL - sklz - skls;
        out[0] = -elbo;
        out[1] = LL;
        out[2] = skl[B_ - 1];
        out[3] = sks[B_ - 1];
    }
}

extern "C" void kernel_launch(void* const* d_in, const int* in_sizes, int n_in,
                              void* d_out, int out_size, void* d_ws, size_t ws_size,
                              hipStream_t stream)
{
    (void)in_sizes; (void)n_in; (void)out_size; (void)ws_size;
    const int*   pidx = (const int*)d_in[0];
    const float* Xc   = (const float*)d_in[1];
    const float* Xb   = (const float*)d_in[2];
    const int*   Xd   = (const int*)d_in[3];
    const float* qm   = (const float*)d_in[4];
    const float* qlv  = (const float*)d_in[5];
    const float* qs   = (const float*)d_in[6];
    const float* pm   = (const float*)d_in[7];
    const float* pv   = (const float*)d_in[8];
    const float* pmu  = (const float*)d_in[9];
    const float* Wg   = (const float*)d_in[10];
    const float* bg   = (const float*)d_in[11];
    const float* lvg  = (const float*)d_in[12];
    const float* Wb   = (const float*)d_in[13];
    const float* bb   = (const float*)d_in[14];
    const float* Wd   = (const float*)d_in[15];
    const float* bd   = (const float*)d_in[16];
    const float* eps  = (const float*)d_in[17];
    float* out = (float*)d_out;
    float* llp = (float*)d_ws;   // M_/2 = 500 partials

    const int nblk = M_ / 2;     // 500 blocks, 2 m-values each
    mm_main_kernel<<<nblk, 512, 0, stream>>>(pidx, Xc, Xb, Xd, qm, qlv, qs,
                                             Wg, bg, lvg, Wb, bb, Wd, bd, eps,
                                             out, llp);
    mm_rik_kernel<<<(N_ * K_ + 255) / 256, 256, 0, stream>>>(pidx, qs, out);
    mm_final_kernel<<<1, 512, 0, stream>>>(pidx, qm, qlv, qs, pm, pv, pmu, llp, nblk, out);
}